// Round 13
// baseline (1845.454 us; speedup 1.0000x reference)
//
#include <hip/hip_runtime.h>
#include <hip/hip_bf16.h>
#include <math.h>

#define N_NODES 50000
#define N_EDGES 200000
#define FIN 128
#define HID 1024
#define NCLS 16
#define EPSN 1e-5f
#define NPAD 50048   // 391 * 128
#define MT 391
#define EPITCH 136   // epilogue LDS pitch: 272B rows stay 16B-aligned (b128-safe).
                     // 132/b64 variant REGRESSED (even-bank aliasing) — keep 136.

typedef __attribute__((ext_vector_type(8))) short short8;
typedef __attribute__((ext_vector_type(8))) unsigned short ushort8;
typedef __attribute__((ext_vector_type(4))) unsigned short u16x4;
typedef __attribute__((ext_vector_type(4))) float f32x4;

static __device__ __forceinline__ float bf2f(unsigned short u) {
  union { unsigned int i; float f; } v; v.i = ((unsigned int)u) << 16; return v.f;
}
static __device__ __forceinline__ unsigned short f2bf(float f) {
  __hip_bfloat16 h = __float2bfloat16(f);
  return *(unsigned short*)&h;
}

#define ASYNC16(gsrc, ldst)                                                   \
  __builtin_amdgcn_global_load_lds(                                           \
      (const __attribute__((address_space(1))) void*)(gsrc),                  \
      (__attribute__((address_space(3))) void*)(ldst), 16, 0, 0)

// ---------------- graph preprocessing ----------------

__global__ __launch_bounds__(256) void k_deg_cnt(const int* __restrict__ dst,
                                                 const float* __restrict__ w,
                                                 float* deg, int* cnt) {
  int e = blockIdx.x * 256 + threadIdx.x;
  if (e < N_EDGES) {
    int d = dst[e];
    atomicAdd(&deg[d], w[e]);
    atomicAdd(&cnt[d], 1);
  }
}

// merged: norm weights (E) + cnt_inv (N)
__global__ __launch_bounds__(256) void k_normw_cntinv(const int* __restrict__ src,
                                                      const int* __restrict__ dst,
                                                      const float* __restrict__ w,
                                                      const float* __restrict__ deg,
                                                      const int* __restrict__ cnt,
                                                      float* __restrict__ normw,
                                                      float* __restrict__ cnt_inv) {
  int e = blockIdx.x * 256 + threadIdx.x;
  if (e < N_EDGES) {
    float ds = deg[src[e]], dd = deg[dst[e]];
    float a = ds > 0.f ? rsqrtf(ds) : 0.f;
    float b = dd > 0.f ? rsqrtf(dd) : 0.f;
    normw[e] = a * w[e] * b;
  }
  if (e < N_NODES) {
    int c = cnt[e];
    cnt_inv[e] = c > 0 ? 1.f / (float)c : 0.f;
  }
}

__global__ __launch_bounds__(1024) void k_scan_a(const int* __restrict__ cnt,
                                                 int* __restrict__ rowptr,
                                                 int* __restrict__ bsums) {
  __shared__ int sm[1024];
  int tid = threadIdx.x;
  int i = blockIdx.x * 1024 + tid;
  int v = (i < N_NODES) ? cnt[i] : 0;
  sm[tid] = v;
  __syncthreads();
  for (int off = 1; off < 1024; off <<= 1) {
    int t = (tid >= off) ? sm[tid - off] : 0;
    __syncthreads();
    sm[tid] += t;
    __syncthreads();
  }
  if (i < N_NODES) rowptr[i] = sm[tid] - v;   // exclusive within block
  if (tid == 1023) bsums[blockIdx.x] = sm[1023];
}

__global__ void k_scan_b(int* bsums, int nb) {
  if (threadIdx.x == 0 && blockIdx.x == 0) {
    int s = 0;
    for (int i = 0; i < nb; ++i) { int t = bsums[i]; bsums[i] = s; s += t; }
  }
}

__global__ __launch_bounds__(1024) void k_scan_c(int* __restrict__ rowptr,
                                                 const int* __restrict__ bsums) {
  int i = blockIdx.x * 1024 + threadIdx.x;
  if (i < N_NODES) rowptr[i] += bsums[blockIdx.x];
}

// fill packed CSR: (src, weight-bits). Weight pre-scaled by cnt_inv[dst]
// (mean-aggr is linear -> exact fold).
__global__ __launch_bounds__(256) void k_fill(const int* __restrict__ src,
                                              const int* __restrict__ dst,
                                              const float* __restrict__ normw,
                                              const float* __restrict__ cnt_inv,
                                              const int* __restrict__ rowptr,
                                              int* __restrict__ fill,
                                              int2* __restrict__ csr_ew) {
  int e = blockIdx.x * 256 + threadIdx.x;
  if (e < N_EDGES) {
    int d = dst[e];
    int pos = rowptr[d] + atomicAdd(&fill[d], 1);
    csr_ew[pos] = make_int2(src[e], __float_as_int(normw[e] * cnt_inv[d]));
  }
}

// ---------------- weight repack (f32 -> bf16, transposed) ----------------

__global__ void k_transpose_bf16(const float* __restrict__ in,
                                 __hip_bfloat16* __restrict__ out, int K, int N) {
  __shared__ float tile[32][33];
  int kb = blockIdx.x * 32, nb = blockIdx.y * 32;
  int tx = threadIdx.x, ty = threadIdx.y;
  for (int i = ty; i < 32; i += 8) tile[i][tx] = in[(size_t)(kb + i) * N + nb + tx];
  __syncthreads();
  for (int i = ty; i < 32; i += 8)
    out[(size_t)(nb + i) * K + kb + tx] = __float2bfloat16(tile[tx][i]);
}

// transpose + per-K scale (K-index mod 1024): folds layer-1 GraphNorm alpha into W2
__global__ void k_transpose_scale_bf16(const float* __restrict__ in,
                                       __hip_bfloat16* __restrict__ out, int K, int N,
                                       const float* __restrict__ alpha) {
  __shared__ float tile[32][33];
  int kb = blockIdx.x * 32, nb = blockIdx.y * 32;
  int tx = threadIdx.x, ty = threadIdx.y;
  for (int i = ty; i < 32; i += 8) tile[i][tx] = in[(size_t)(kb + i) * N + nb + tx];
  __syncthreads();
  float sc = alpha[(kb + tx) & (HID - 1)];
  for (int i = ty; i < 32; i += 8)
    out[(size_t)(nb + i) * K + kb + tx] = __float2bfloat16(tile[tx][i] * sc);
}

// ck[k3][c] += sum_{16-row chunk} beta[in] * W2[k3,in,c]; grid (4,64) = 256 blocks
// (64-block version was 0.25 blocks/CU — latency straggler)
__global__ __launch_bounds__(256) void k_ck_part(const float* __restrict__ W2,
                                                 const float* __restrict__ beta,
                                                 const float* __restrict__ b2,
                                                 float* __restrict__ ck) {
  int k3 = blockIdx.x;        // 0..3
  int ch = blockIdx.y;        // 0..63
  int tid = threadIdx.x;
  float acc[4] = {0.f, 0.f, 0.f, 0.f};
  const float* Wk = W2 + (size_t)k3 * HID * HID;
  int i0 = ch * 16;
  for (int in = i0; in < i0 + 16; ++in) {
    float s = beta[in];
    const float* row = Wk + (size_t)in * HID;
#pragma unroll
    for (int j = 0; j < 4; ++j) acc[j] += s * row[tid + j * 256];
  }
#pragma unroll
  for (int j = 0; j < 4; ++j) {
    float v = acc[j];
    if (k3 == 0 && ch == 0) v += b2[tid + j * 256];
    atomicAdd(&ck[k3 * HID + tid + j * 256], v);
  }
}

// ck3[b] = sum_in beta2[in] * W3[k,in,j], b=k*16+j — 64 blocks x 256 threads
// (1-block version was a single-CU straggler)
__global__ __launch_bounds__(256) void k_ck3(const float* __restrict__ W3,
                                             const float* __restrict__ beta,
                                             float* __restrict__ ck3) {
  __shared__ float sm[256];
  int b = blockIdx.x;
  int k = b >> 4, j = b & 15;
  int tid = threadIdx.x;
  float acc = 0.f;
  for (int in = tid; in < HID; in += 256)
    acc += beta[in] * W3[((size_t)k * HID + in) * 16 + j];
  sm[tid] = acc;
  __syncthreads();
  for (int s = 128; s > 0; s >>= 1) {
    if (tid < s) sm[tid] += sm[tid + s];
    __syncthreads();
  }
  if (tid == 0) ck3[b] = sm[0];
}

// W3 [4,1024,16] -> W3T[k3*16+j][k] bf16 (pitch 1024), scaled by alpha2[k]
__global__ __launch_bounds__(256) void k_packw3(const float* __restrict__ W3,
                                                __hip_bfloat16* __restrict__ W3T,
                                                const float* __restrict__ alpha) {
  int idx = blockIdx.x * 256 + threadIdx.x;
  if (idx < 4 * 1024 * 16) {
    int k3 = idx >> 14, r = idx & 16383, k = r >> 4, j = r & 15;
    W3T[(size_t)(k3 * 16 + j) * 1024 + k] = __float2bfloat16(W3[idx] * alpha[k]);
  }
}

// x [N,128] f32 -> Xcat [N, pitch 512] bf16
__global__ __launch_bounds__(256) void k_x_to_bf16(const float* __restrict__ x,
                                                   unsigned short* __restrict__ xc) {
  int i = blockIdx.x * 256 + threadIdx.x;   // group of 4 floats
  if (i < N_NODES * FIN / 4) {
    int n = i >> 5, c4 = i & 31;
    const float4 v = ((const float4*)x)[i];
    u16x4 o;
    o[0] = f2bf(v.x); o[1] = f2bf(v.y); o[2] = f2bf(v.z); o[3] = f2bf(v.w);
    *(u16x4*)&xc[(size_t)n * 512 + c4 * 4] = o;
  }
}

// ---------------- SpMM (CSR packed int2, bf16 -> bf16) ----------------
// Each node handled by W/8 lanes; each lane owns 8 features (16 B gathers).
// Weights pre-scaled by cnt_inv. Edge loop unrolled x2. (FPL=8 validated;
// FPL=16 REGRESSED in R11.)

template <int W>
__global__ __launch_bounds__(256) void k_spmm_v(
    const unsigned short* __restrict__ src_t, int sp,
    unsigned short* __restrict__ dst_t, int dp,
    const int* __restrict__ rowptr, const int* __restrict__ cnt,
    const int2* __restrict__ csr_ew) {
  constexpr int G = W / 8;          // lanes per node
  int gl = blockIdx.x * 256 + threadIdx.x;
  int node = gl / G;
  if (node >= N_NODES) return;
  int fl = (gl % G) * 8;
  int beg = rowptr[node], end = beg + cnt[node];
  float acc[8] = {0.f, 0.f, 0.f, 0.f, 0.f, 0.f, 0.f, 0.f};
  int i = beg;
  for (; i + 1 < end; i += 2) {
    int2 e0 = csr_ew[i], e1 = csr_ew[i + 1];
    float w0 = __int_as_float(e0.y), w1 = __int_as_float(e1.y);
    ushort8 v0 = *(const ushort8*)&src_t[(size_t)e0.x * sp + fl];
    ushort8 v1 = *(const ushort8*)&src_t[(size_t)e1.x * sp + fl];
#pragma unroll
    for (int j = 0; j < 8; ++j) acc[j] += w0 * bf2f(v0[j]) + w1 * bf2f(v1[j]);
  }
  if (i < end) {
    int2 e0 = csr_ew[i];
    float w0 = __int_as_float(e0.y);
    ushort8 v0 = *(const ushort8*)&src_t[(size_t)e0.x * sp + fl];
#pragma unroll
    for (int j = 0; j < 8; ++j) acc[j] += w0 * bf2f(v0[j]);
  }
  ushort8 o;
#pragma unroll
  for (int j = 0; j < 8; ++j) o[j] = f2bf(acc[j]);
  *(ushort8*)&dst_t[(size_t)node * dp + fl] = o;
}

// 16-wide fp32 SpMM with addend (Horner for layer 3); weights pre-scaled
__global__ __launch_bounds__(256) void k_spmm16(const float* __restrict__ src_t, int sp,
                                                const float* __restrict__ addend, int ap,
                                                const float* __restrict__ b3,
                                                float* __restrict__ out, int op,
                                                const int* __restrict__ rowptr,
                                                const int* __restrict__ cnt,
                                                const int2* __restrict__ csr_ew) {
  int idx = blockIdx.x * 256 + threadIdx.x;
  if (idx >= N_NODES * 16) return;
  int node = idx >> 4, f = idx & 15;
  int beg = rowptr[node], ne = cnt[node];
  float acc = 0.f;
  for (int i = 0; i < ne; ++i) {
    int2 e = csr_ew[beg + i];
    acc += __int_as_float(e.y) * src_t[(size_t)e.x * sp + f];
  }
  float r = acc + addend[(size_t)node * ap + f];
  if (b3) r += b3[f];
  out[(size_t)node * op + f] = r;
}

// ---- bf16 MFMA GEMM (R10-proven core): Cout = A*BT^T (+ Cinit) ----
// 128x128 tile, BK=32 double-buffered, 4 waves (2x2), 4x4 MFMA 16x16x32.
// global_load_lds width 16; XOR swizzle; LDS-staged coalesced bf16 epilogue.
// STATS/ATOMIC are COMPILE-TIME template args; <0,0> must codegen identically
// to the validated R10 kernel. ATOMIC=1: blockIdx.x selects a K/4 chunk
// (single N-tile, Nout<=128), f32 atomicAdd into pre-zeroed Cout, bias from
// chunk 0 only — fixes the 1.5-blocks/CU L3-projection straggler.

template <int STATS, int ATOMIC = 0>
__global__ __launch_bounds__(256, 4) void k_gemm(
    const unsigned short* __restrict__ A, int lda,
    const unsigned short* __restrict__ BT, int ldb,
    const unsigned short* __restrict__ Cinit, int ldci,
    void* __restrict__ Cout, int ldc, int cbf16,
    int M, int Nout, int K,
    const float* __restrict__ bias, int do_elu,
    float* __restrict__ stats_out, int stats_off) {
  __shared__ __align__(16) unsigned short smem[128 * EPITCH];  // 34816 B
  int tid = threadIdx.x;
  int wave = tid >> 6, lane = tid & 63;
  int wm = wave >> 1, wn = wave & 1;
  int l15 = lane & 15, quad = lane >> 4;
  int im = blockIdx.y;
  int in_ = ATOMIC ? 0 : blockIdx.x;
  int kbeg = ATOMIC ? (int)blockIdx.x * (K >> 2) : 0;
  int kend = ATOMIC ? kbeg + (K >> 2) : K;

  f32x4 acc[4][4];
  if (Cinit) {
    {
      int r = tid >> 1, hf = tid & 1;
      const unsigned short* gsrc =
          &Cinit[(size_t)(im * 128 + r) * ldci + in_ * 128 + hf * 64];
#pragma unroll
      for (int v = 0; v < 8; ++v)
        *(ushort8*)&smem[r * EPITCH + hf * 64 + v * 8] = *(const ushort8*)&gsrc[v * 8];
    }
    __syncthreads();
#pragma unroll
    for (int i = 0; i < 4; ++i)
#pragma unroll
      for (int j = 0; j < 4; ++j)
#pragma unroll
        for (int reg = 0; reg < 4; ++reg)
          acc[i][j][reg] =
              bf2f(smem[(wm * 64 + i * 16 + quad * 4 + reg) * EPITCH + wn * 64 + j * 16 + l15]);
    __syncthreads();
  } else {
#pragma unroll
    for (int i = 0; i < 4; ++i)
#pragma unroll
      for (int j = 0; j < 4; ++j) acc[i][j] = (f32x4){0.f, 0.f, 0.f, 0.f};
  }

  int srow = tid >> 2;                                       // 0..63
  int sl = (tid & 3) ^ (srow & 3) ^ ((srow >> 2) & 3);       // swizzled chunk
  const unsigned short* gA0 = &A[(size_t)(im * 128 + srow) * lda + sl * 8];
  const unsigned short* gA1 = &A[(size_t)(im * 128 + 64 + srow) * lda + sl * 8];
  const unsigned short* gB0 = &BT[(size_t)(in_ * 128 + srow) * ldb + sl * 8];
  const unsigned short* gB1 = &BT[(size_t)(in_ * 128 + 64 + srow) * ldb + sl * 8];
  unsigned short* ldsA = smem;            // [2][4096]
  unsigned short* ldsB = smem + 8192;     // [2][4096]
  int woff0 = (wave * 64) * 8;
  int woff1 = (256 + wave * 64) * 8;
  int rsl = (quad ^ (l15 & 3) ^ (l15 >> 2)) * 8;

  auto stage = [&](int k0, int p) {
    ASYNC16(gA0 + k0, &ldsA[p * 4096 + woff0]);
    ASYNC16(gA1 + k0, &ldsA[p * 4096 + woff1]);
    ASYNC16(gB0 + k0, &ldsB[p * 4096 + woff0]);
    ASYNC16(gB1 + k0, &ldsB[p * 4096 + woff1]);
  };
  auto compute = [&](int p) {
    short8 af[4], bf[4];
#pragma unroll
    for (int i = 0; i < 4; ++i)
      af[i] = *(const short8*)&ldsA[p * 4096 + (wm * 64 + i * 16 + l15) * 32 + rsl];
#pragma unroll
    for (int j = 0; j < 4; ++j)
      bf[j] = *(const short8*)&ldsB[p * 4096 + (wn * 64 + j * 16 + l15) * 32 + rsl];
#pragma unroll
    for (int i = 0; i < 4; ++i)
#pragma unroll
      for (int j = 0; j < 4; ++j)
        acc[i][j] = __builtin_amdgcn_mfma_f32_16x16x32_bf16(af[i], bf[j], acc[i][j], 0, 0, 0);
  };

  stage(kbeg, 0);
  __syncthreads();
  int p = 0;
  for (int k0 = kbeg + 32; k0 < kend; k0 += 32) {
    stage(k0, p ^ 1);
    compute(p);
    __syncthreads();
    p ^= 1;
  }
  compute(p);
  __syncthreads();

  if (cbf16) {
    float sl0[4], sl2[4];
    if (STATS) {
#pragma unroll
      for (int j = 0; j < 4; ++j) { sl0[j] = 0.f; sl2[j] = 0.f; }
    }
#pragma unroll
    for (int i = 0; i < 4; ++i)
#pragma unroll
      for (int j = 0; j < 4; ++j) {
        int cg = in_ * 128 + wn * 64 + j * 16 + l15;
        float bv = bias ? bias[cg] : 0.f;
#pragma unroll
        for (int reg = 0; reg < 4; ++reg) {
          float v = acc[i][j][reg] + bv;
          if (do_elu) v = v > 0.f ? v : expm1f(v);
          unsigned short b = f2bf(v);
          smem[(wm * 64 + i * 16 + quad * 4 + reg) * EPITCH + wn * 64 + j * 16 + l15] = b;
          if (STATS) {
            int r = im * 128 + wm * 64 + i * 16 + quad * 4 + reg;
            if (r < M) {
              float vq = bf2f(b);
              sl0[j] += vq; sl2[j] += vq * vq;
            }
          }
        }
      }
    __syncthreads();
    {
      int r = tid >> 1, hf = tid & 1;
      unsigned short* gdst =
          (unsigned short*)Cout + (size_t)(im * 128 + r) * ldc + in_ * 128 + hf * 64;
#pragma unroll
      for (int v = 0; v < 8; ++v)
        *(ushort8*)&gdst[v * 8] = *(const ushort8*)&smem[r * EPITCH + hf * 64 + v * 8];
    }
    if (STATS) {
      __syncthreads();   // tile fully consumed -> reuse smem as f32 scratch
      float* fs = (float*)smem;           // [2][8][128] = 8 KB
      int slot = wm * 4 + quad;           // 0..7
#pragma unroll
      for (int j = 0; j < 4; ++j) {
        int c = wn * 64 + j * 16 + l15;   // 0..127
        fs[slot * 128 + c] = sl0[j];
        fs[1024 + slot * 128 + c] = sl2[j];
      }
      __syncthreads();
      if (tid < 128) {
        float a0 = 0.f, a1 = 0.f;
#pragma unroll
        for (int s = 0; s < 8; ++s) {
          a0 += fs[s * 128 + tid];
          a1 += fs[1024 + s * 128 + tid];
        }
        atomicAdd(&stats_out[stats_off + in_ * 128 + tid], a0);
        atomicAdd(&stats_out[HID + stats_off + in_ * 128 + tid], a1);
      }
    }
  } else {
#pragma unroll
    for (int i = 0; i < 4; ++i) {
      int r0 = im * 128 + wm * 64 + i * 16 + quad * 4;
#pragma unroll
      for (int j = 0; j < 4; ++j) {
        int c = in_ * 128 + wn * 64 + j * 16 + l15;
        if (c < Nout) {
#pragma unroll
          for (int reg = 0; reg < 4; ++reg) {
            int r = r0 + reg;
            if (r < M) {
              float v = acc[i][j][reg];
              if (bias && (!ATOMIC || blockIdx.x == 0)) v += bias[c];
              if (do_elu) v = v > 0.f ? v : expm1f(v);
              if (ATOMIC)
                atomicAdd(&((float*)Cout)[(size_t)r * ldc + c], v);
              else
                ((float*)Cout)[(size_t)r * ldc + c] = v;
            }
          }
        }
      }
    }
  }
}

// ---------------- GraphNorm finalize ----------------

__global__ __launch_bounds__(256) void k_finalize(const float* __restrict__ g,
                                                  const float* __restrict__ be,
                                                  const float* __restrict__ a,
                                                  float* __restrict__ stats) {
  int f = blockIdx.x * 256 + threadIdx.x;
  if (f < HID) {
    float m = stats[f] / (float)N_NODES;
    float ex2 = stats[HID + f] / (float)N_NODES;
    float av = a[f];
    float var = ex2 - 2.f * av * m * m + av * av * m * m;  // E[(x-a*m)^2]
    float alpha = g[f] * rsqrtf(var + EPSN);
    stats[2 * HID + f] = alpha;
    stats[3 * HID + f] = be[f] - alpha * av * m;
  }
}

// ---------------- launch ----------------

extern "C" void kernel_launch(void* const* d_in, const int* in_sizes, int n_in,
                              void* d_out, int out_size, void* d_ws, size_t ws_size,
                              hipStream_t stream) {
  const float* x   = (const float*)d_in[0];
  const int*   ei  = (const int*)d_in[1];
  const float* w   = (const float*)d_in[2];
  const float* W1  = (const float*)d_in[3];
  const float* b1  = (const float*)d_in[4];
  const float* g1  = (const float*)d_in[5];
  const float* be1 = (const float*)d_in[6];
  const float* a1  = (const float*)d_in[7];
  const float* W2  = (const float*)d_in[8];
  const float* b2  = (const float*)d_in[9];
  const float* g2  = (const float*)d_in[10];
  const float* be2 = (const float*)d_in[11];
  const float* a2  = (const float*)d_in[12];
  const float* W3  = (const float*)d_in[13];
  const float* b3  = (const float*)d_in[14];
  float* out = (float*)d_out;

  const int* srcI = ei;
  const int* dstI = ei + N_EDGES;

  char* base = (char*)d_ws;
  size_t off = 0;
  auto alloc = [&](size_t bytes) -> char* {
    char* p = base + off;
    off += (bytes + 255) & ~(size_t)255;
    return p;
  };

  // small buffers
  float* deg      = (float*)alloc(N_NODES * 4);
  int*   cnt      = (int*)alloc(N_NODES * 4);
  float* cnt_inv  = (float*)alloc(N_NODES * 4);
  float* normw    = (float*)alloc(N_EDGES * 4);
  int*   rowptr   = (int*)alloc((N_NODES + 1) * 4);
  int*   fill     = (int*)alloc(N_NODES * 4);
  int*   bsums    = (int*)alloc(64 * 4);
  int2*  csr_ew   = (int2*)alloc((size_t)N_EDGES * 8);
  float* stats    = (float*)alloc(4 * HID * 4);
  float* ck       = (float*)alloc(4 * HID * 4);
  float* ck3      = (float*)alloc(64 * 4);
  // weights (~9.7 MB)
  __hip_bfloat16* W1T = (__hip_bfloat16*)alloc((size_t)1024 * 512 * 2);
  __hip_bfloat16* W2T = (__hip_bfloat16*)alloc((size_t)1024 * 4096 * 2);
  __hip_bfloat16* W3T = (__hip_bfloat16*)alloc((size_t)128 * 1024 * 2);
  // full node tables (102.5 MB each)
  const size_t FT = (size_t)NPAD * HID * 2;
  unsigned short* T0 = (unsigned short*)alloc(FT);
  unsigned short* T1 = (unsigned short*)alloc(FT);
  size_t rem = (ws_size > off) ? (ws_size - off) : 0;
  bool full = rem >= FT + 1024;
  unsigned short *T2 = nullptr, *Q = nullptr, *R = nullptr;
  int wcols = 0;
  if (full) {
    T2 = (unsigned short*)alloc(FT);
  } else {
    wcols = 512;
    if (rem < 2 * (size_t)NPAD * 512 * 2 + 1024) wcols = 256;
    if (wcols == 256 && rem < 2 * (size_t)NPAD * 256 * 2 + 1024) wcols = 128;
    Q = (unsigned short*)alloc((size_t)NPAD * wcols * 2);
    R = (unsigned short*)alloc((size_t)NPAD * wcols * 2);
  }
  // layer-3 scratch carved from T0 (dead after last layer-2 GEMM)
  float* Z  = (float*)T0;
  float* t0 = (float*)((char*)T0 + (size_t)16 * 1024 * 1024);
  float* t1 = (float*)((char*)T0 + (size_t)24 * 1024 * 1024);
  (void)n_in; (void)in_sizes; (void)out_size;

  const int EB = (N_EDGES + 255) / 256;

  // graph preprocessing + CSR
  (void)hipMemsetAsync(deg, 0, N_NODES * 4, stream);
  (void)hipMemsetAsync(cnt, 0, N_NODES * 4, stream);
  (void)hipMemsetAsync(fill, 0, N_NODES * 4, stream);
  k_deg_cnt<<<EB, 256, 0, stream>>>(dstI, w, deg, cnt);
  k_normw_cntinv<<<EB, 256, 0, stream>>>(srcI, dstI, w, deg, cnt, normw, cnt_inv);
  k_scan_a<<<49, 1024, 0, stream>>>(cnt, rowptr, bsums);
  k_scan_b<<<1, 64, 0, stream>>>(bsums, 49);
  k_scan_c<<<49, 1024, 0, stream>>>(rowptr, bsums);
  k_fill<<<EB, 256, 0, stream>>>(srcI, dstI, normw, cnt_inv, rowptr, fill, csr_ew);

  // W1 repack (W2/W3 repacks happen after the respective finalize — alpha fold)
  k_transpose_bf16<<<dim3(512 / 32, 1024 / 32), dim3(32, 8), 0, stream>>>(W1, W1T, 512, 1024);

  const unsigned short* W2Tu = (const unsigned short*)W2T;

  // ---- layer 1: Xcat [N, 4*128] in T1 (pitch 512), GEMM K=512 -> T0 (+stats) ----
  k_x_to_bf16<<<(N_NODES * FIN / 4 + 255) / 256, 256, 0, stream>>>(x, T1);
  {
    int blocks = (N_NODES * 16 + 255) / 256;
    for (int k = 1; k <= 3; ++k)
      k_spmm_v<128><<<blocks, 256, 0, stream>>>(
          T1 + (k - 1) * FIN, 512, T1 + k * FIN, 512,
          rowptr, cnt, csr_ew);
  }
  (void)hipMemsetAsync(stats, 0, 2 * HID * 4, stream);
  k_gemm<1><<<dim3(8, MT), 256, 0, stream>>>(
      T1, 512, (const unsigned short*)W1T, 512,
      nullptr, 0, T0, HID, 1, N_NODES, HID, 512, b1, 1, stats, 0);
  k_finalize<<<4, 256, 0, stream>>>(g1, be1, a1, stats);
  // GraphNorm-1 folded into W2 (alpha-scaled repack + ck bias)
  k_transpose_scale_bf16<<<dim3(4096 / 32, 1024 / 32), dim3(32, 8), 0, stream>>>(
      W2, W2T, 4096, 1024, stats + 2 * HID);
  (void)hipMemsetAsync(ck, 0, 4 * HID * 4, stream);
  k_ck_part<<<dim3(4, 64), 256, 0, stream>>>(W2, stats + 3 * HID, b2, ck);

  // ---- layer 2: Horner; hop-0 GEMM fuses ELU + column stats ----
  if (full) {
    const int SPB = (N_NODES * 128 + 255) / 256;
    k_gemm<0><<<dim3(8, MT), 256, 0, stream>>>(
        T0, 1024, W2Tu + 3 * 1024, 4096,
        nullptr, 0, T1, 1024, 1, N_NODES, 1024, 1024, ck + 3 * 1024, 0, nullptr, 0);
    k_spmm_v<1024><<<SPB, 256, 0, stream>>>(T1, 1024, T2, 1024,
                                            rowptr, cnt, csr_ew);
    k_gemm<0><<<dim3(8, MT), 256, 0, stream>>>(
        T0, 1024, W2Tu + 2 * 1024, 4096,
        T2, 1024, T1, 1024, 1, N_NODES, 1024, 1024, ck + 2 * 1024, 0, nullptr, 0);
    k_spmm_v<1024><<<SPB, 256, 0, stream>>>(T1, 1024, T2, 1024,
                                            rowptr, cnt, csr_ew);
    k_gemm<0><<<dim3(8, MT), 256, 0, stream>>>(
        T0, 1024, W2Tu + 1 * 1024, 4096,
        T2, 1024, T1, 1024, 1, N_NODES, 1024, 1024, ck + 1 * 1024, 0, nullptr, 0);
    k_spmm_v<1024><<<SPB, 256, 0, stream>>>(T1, 1024, T2, 1024,
                                            rowptr, cnt, csr_ew);
    (void)hipMemsetAsync(stats, 0, 2 * HID * 4, stream);
    k_gemm<1><<<dim3(8, MT), 256, 0, stream>>>(
        T0, 1024, W2Tu + 0 * 1024, 4096,
        T2, 1024, T1, 1024, 1, N_NODES, 1024, 1024, ck + 0 * 1024, 1, stats, 0);
  } else {
    auto spmm_w = [&](const unsigned short* s, unsigned short* d) {
      int blocks = (N_NODES * (wcols / 8) + 255) / 256;
      if (wcols == 512)
        k_spmm_v<512><<<blocks, 256, 0, stream>>>(s, wcols, d, wcols,
            rowptr, cnt, csr_ew);
      else if (wcols == 256)
        k_spmm_v<256><<<blocks, 256, 0, stream>>>(s, wcols, d, wcols,
            rowptr, cnt, csr_ew);
      else
        k_spmm_v<128><<<blocks, 256, 0, stream>>>(s, wcols, d, wcols,
            rowptr, cnt, csr_ew);
    };
    (void)hipMemsetAsync(stats, 0, 2 * HID * 4, stream);
    for (int c = 0; c < HID; c += wcols) {
      const unsigned short* Wb = W2Tu + (size_t)c * 4096;
      k_gemm<0><<<dim3(wcols / 128, MT), 256, 0, stream>>>(
          T0, 1024, Wb + 3 * 1024, 4096,
          nullptr, 0, Q, wcols, 1, N_NODES, wcols, 1024, ck + 3 * 1024 + c, 0, nullptr, 0);
      spmm_w(Q, R);
      k_gemm<0><<<dim3(wcols / 128, MT), 256, 0, stream>>>(
          T0, 1024, Wb + 2 * 1024, 4096,
          R, wcols, Q, wcols, 1, N_NODES, wcols, 1024, ck + 2 * 1024 + c, 0, nullptr, 0);
      spmm_w(Q, R);
      k_gemm<0><<<dim3(wcols / 128, MT), 256, 0, stream>>>(
          T0, 1024, Wb + 1 * 1024, 4096,
          R, wcols, Q, wcols, 1, N_NODES, wcols, 1024, ck + 1 * 1024 + c, 0, nullptr, 0);
      spmm_w(Q, R);
      k_gemm<1><<<dim3(wcols / 128, MT), 256, 0, stream>>>(
          T0, 1024, Wb + 0 * 1024, 4096,
          R, wcols, T1 + c, 1024, 1, N_NODES, wcols, 1024, ck + 0 * 1024 + c, 1, stats, c);
    }
  }
  k_finalize<<<4, 256, 0, stream>>>(g2, be2, a2, stats);
  // GraphNorm-2 folded into W3 (alpha-scaled repack + ck3 bias)
  k_packw3<<<(65536 + 255) / 256, 256, 0, stream>>>(W3, W3T, stats + 2 * HID);
  k_ck3<<<64, 256, 0, stream>>>(W3, stats + 3 * HID, ck3);

  // ---- layer 3: project via K-split x4 atomic GEMM (Z pre-zeroed), then
  //      Horner width 16 ----
  (void)hipMemsetAsync(Z, 0, (size_t)N_NODES * 64 * 4, stream);
  k_gemm<0, 1><<<dim3(4, MT), 256, 0, stream>>>(
      T1, 1024, (const unsigned short*)W3T, 1024,
      nullptr, 0, Z, 64, 0, N_NODES, 64, 1024, ck3, 0, nullptr, 0);
  const int SB = (N_NODES * 16 + 255) / 256;
  k_spmm16<<<SB, 256, 0, stream>>>(Z + 48, 64, Z + 32, 64, nullptr, t0, 16,
                                   rowptr, cnt, csr_ew);
  k_spmm16<<<SB, 256, 0, stream>>>(t0, 16, Z + 16, 64, nullptr, t1, 16,
                                   rowptr, cnt, csr_ew);
  k_spmm16<<<SB, 256, 0, stream>>>(t1, 16, Z + 0, 64, b3, out, 16,
                                   rowptr, cnt, csr_ew);
}

// Round 14
// 1799.423 us; speedup vs baseline: 1.0256x; 1.0256x over previous
//
#include <hip/hip_runtime.h>
#include <hip/hip_bf16.h>
#include <math.h>

#define N_NODES 50000
#define N_EDGES 200000
#define FIN 128
#define HID 1024
#define NCLS 16
#define EPSN 1e-5f
#define NPAD 50048   // 391 * 128
#define MT 391
#define EPITCH 136   // epilogue LDS pitch: 272B rows stay 16B-aligned (b128-safe).
                     // 132/b64 variant REGRESSED (even-bank aliasing) — keep 136.

typedef __attribute__((ext_vector_type(8))) short short8;
typedef __attribute__((ext_vector_type(8))) unsigned short ushort8;
typedef __attribute__((ext_vector_type(4))) unsigned short u16x4;
typedef __attribute__((ext_vector_type(4))) float f32x4;

static __device__ __forceinline__ float bf2f(unsigned short u) {
  union { unsigned int i; float f; } v; v.i = ((unsigned int)u) << 16; return v.f;
}
static __device__ __forceinline__ unsigned short f2bf(float f) {
  __hip_bfloat16 h = __float2bfloat16(f);
  return *(unsigned short*)&h;
}

#define ASYNC16(gsrc, ldst)                                                   \
  __builtin_amdgcn_global_load_lds(                                           \
      (const __attribute__((address_space(1))) void*)(gsrc),                  \
      (__attribute__((address_space(3))) void*)(ldst), 16, 0, 0)

// ---------------- graph preprocessing ----------------

__global__ __launch_bounds__(256) void k_deg_cnt(const int* __restrict__ dst,
                                                 const float* __restrict__ w,
                                                 float* deg, int* cnt) {
  int e = blockIdx.x * 256 + threadIdx.x;
  if (e < N_EDGES) {
    int d = dst[e];
    atomicAdd(&deg[d], w[e]);
    atomicAdd(&cnt[d], 1);
  }
}

// merged: norm weights (E) + cnt_inv (N)
__global__ __launch_bounds__(256) void k_normw_cntinv(const int* __restrict__ src,
                                                      const int* __restrict__ dst,
                                                      const float* __restrict__ w,
                                                      const float* __restrict__ deg,
                                                      const int* __restrict__ cnt,
                                                      float* __restrict__ normw,
                                                      float* __restrict__ cnt_inv) {
  int e = blockIdx.x * 256 + threadIdx.x;
  if (e < N_EDGES) {
    float ds = deg[src[e]], dd = deg[dst[e]];
    float a = ds > 0.f ? rsqrtf(ds) : 0.f;
    float b = dd > 0.f ? rsqrtf(dd) : 0.f;
    normw[e] = a * w[e] * b;
  }
  if (e < N_NODES) {
    int c = cnt[e];
    cnt_inv[e] = c > 0 ? 1.f / (float)c : 0.f;
  }
}

__global__ __launch_bounds__(1024) void k_scan_a(const int* __restrict__ cnt,
                                                 int* __restrict__ rowptr,
                                                 int* __restrict__ bsums) {
  __shared__ int sm[1024];
  int tid = threadIdx.x;
  int i = blockIdx.x * 1024 + tid;
  int v = (i < N_NODES) ? cnt[i] : 0;
  sm[tid] = v;
  __syncthreads();
  for (int off = 1; off < 1024; off <<= 1) {
    int t = (tid >= off) ? sm[tid - off] : 0;
    __syncthreads();
    sm[tid] += t;
    __syncthreads();
  }
  if (i < N_NODES) rowptr[i] = sm[tid] - v;   // exclusive within block
  if (tid == 1023) bsums[blockIdx.x] = sm[1023];
}

__global__ void k_scan_b(int* bsums, int nb) {
  if (threadIdx.x == 0 && blockIdx.x == 0) {
    int s = 0;
    for (int i = 0; i < nb; ++i) { int t = bsums[i]; bsums[i] = s; s += t; }
  }
}

__global__ __launch_bounds__(1024) void k_scan_c(int* __restrict__ rowptr,
                                                 const int* __restrict__ bsums) {
  int i = blockIdx.x * 1024 + threadIdx.x;
  if (i < N_NODES) rowptr[i] += bsums[blockIdx.x];
}

// fill packed CSR: (src, weight-bits). Weight pre-scaled by cnt_inv[dst]
// (mean-aggr is linear -> exact fold).
__global__ __launch_bounds__(256) void k_fill(const int* __restrict__ src,
                                              const int* __restrict__ dst,
                                              const float* __restrict__ normw,
                                              const float* __restrict__ cnt_inv,
                                              const int* __restrict__ rowptr,
                                              int* __restrict__ fill,
                                              int2* __restrict__ csr_ew) {
  int e = blockIdx.x * 256 + threadIdx.x;
  if (e < N_EDGES) {
    int d = dst[e];
    int pos = rowptr[d] + atomicAdd(&fill[d], 1);
    csr_ew[pos] = make_int2(src[e], __float_as_int(normw[e] * cnt_inv[d]));
  }
}

// ---------------- weight repack (f32 -> bf16, transposed) ----------------

__global__ void k_transpose_bf16(const float* __restrict__ in,
                                 __hip_bfloat16* __restrict__ out, int K, int N) {
  __shared__ float tile[32][33];
  int kb = blockIdx.x * 32, nb = blockIdx.y * 32;
  int tx = threadIdx.x, ty = threadIdx.y;
  for (int i = ty; i < 32; i += 8) tile[i][tx] = in[(size_t)(kb + i) * N + nb + tx];
  __syncthreads();
  for (int i = ty; i < 32; i += 8)
    out[(size_t)(nb + i) * K + kb + tx] = __float2bfloat16(tile[tx][i]);
}

// transpose + per-K scale (K-index mod 1024): folds layer-1 GraphNorm alpha into W2
__global__ void k_transpose_scale_bf16(const float* __restrict__ in,
                                       __hip_bfloat16* __restrict__ out, int K, int N,
                                       const float* __restrict__ alpha) {
  __shared__ float tile[32][33];
  int kb = blockIdx.x * 32, nb = blockIdx.y * 32;
  int tx = threadIdx.x, ty = threadIdx.y;
  for (int i = ty; i < 32; i += 8) tile[i][tx] = in[(size_t)(kb + i) * N + nb + tx];
  __syncthreads();
  float sc = alpha[(kb + tx) & (HID - 1)];
  for (int i = ty; i < 32; i += 8)
    out[(size_t)(nb + i) * K + kb + tx] = __float2bfloat16(tile[tx][i] * sc);
}

// ck[k3][c] += sum_{16-row chunk} beta[in] * W2[k3,in,c]; grid (4,64) = 256 blocks
__global__ __launch_bounds__(256) void k_ck_part(const float* __restrict__ W2,
                                                 const float* __restrict__ beta,
                                                 const float* __restrict__ b2,
                                                 float* __restrict__ ck) {
  int k3 = blockIdx.x;        // 0..3
  int ch = blockIdx.y;        // 0..63
  int tid = threadIdx.x;
  float acc[4] = {0.f, 0.f, 0.f, 0.f};
  const float* Wk = W2 + (size_t)k3 * HID * HID;
  int i0 = ch * 16;
  for (int in = i0; in < i0 + 16; ++in) {
    float s = beta[in];
    const float* row = Wk + (size_t)in * HID;
#pragma unroll
    for (int j = 0; j < 4; ++j) acc[j] += s * row[tid + j * 256];
  }
#pragma unroll
  for (int j = 0; j < 4; ++j) {
    float v = acc[j];
    if (k3 == 0 && ch == 0) v += b2[tid + j * 256];
    atomicAdd(&ck[k3 * HID + tid + j * 256], v);
  }
}

// ck3[b] = sum_in beta2[in] * W3[k,in,j], b=k*16+j — 64 blocks x 256 threads
__global__ __launch_bounds__(256) void k_ck3(const float* __restrict__ W3,
                                             const float* __restrict__ beta,
                                             float* __restrict__ ck3) {
  __shared__ float sm[256];
  int b = blockIdx.x;
  int k = b >> 4, j = b & 15;
  int tid = threadIdx.x;
  float acc = 0.f;
  for (int in = tid; in < HID; in += 256)
    acc += beta[in] * W3[((size_t)k * HID + in) * 16 + j];
  sm[tid] = acc;
  __syncthreads();
  for (int s = 128; s > 0; s >>= 1) {
    if (tid < s) sm[tid] += sm[tid + s];
    __syncthreads();
  }
  if (tid == 0) ck3[b] = sm[0];
}

// W3 [4,1024,16] -> W3T[k3*16+j][k] bf16 (pitch 1024), scaled by alpha2[k]
__global__ __launch_bounds__(256) void k_packw3(const float* __restrict__ W3,
                                                __hip_bfloat16* __restrict__ W3T,
                                                const float* __restrict__ alpha) {
  int idx = blockIdx.x * 256 + threadIdx.x;
  if (idx < 4 * 1024 * 16) {
    int k3 = idx >> 14, r = idx & 16383, k = r >> 4, j = r & 15;
    W3T[(size_t)(k3 * 16 + j) * 1024 + k] = __float2bfloat16(W3[idx] * alpha[k]);
  }
}

// x [N,128] f32 -> Xcat [N, pitch 512] bf16
__global__ __launch_bounds__(256) void k_x_to_bf16(const float* __restrict__ x,
                                                   unsigned short* __restrict__ xc) {
  int i = blockIdx.x * 256 + threadIdx.x;   // group of 4 floats
  if (i < N_NODES * FIN / 4) {
    int n = i >> 5, c4 = i & 31;
    const float4 v = ((const float4*)x)[i];
    u16x4 o;
    o[0] = f2bf(v.x); o[1] = f2bf(v.y); o[2] = f2bf(v.z); o[3] = f2bf(v.w);
    *(u16x4*)&xc[(size_t)n * 512 + c4 * 4] = o;
  }
}

// ---------------- SpMM (CSR packed int2, bf16 -> bf16) ----------------
// Each node handled by W/8 lanes; each lane owns 8 features (16 B gathers).
// Weights pre-scaled by cnt_inv. Edge loop unrolled x2. (FPL=8 validated;
// FPL=16 REGRESSED in R11.)

template <int W>
__global__ __launch_bounds__(256) void k_spmm_v(
    const unsigned short* __restrict__ src_t, int sp,
    unsigned short* __restrict__ dst_t, int dp,
    const int* __restrict__ rowptr, const int* __restrict__ cnt,
    const int2* __restrict__ csr_ew) {
  constexpr int G = W / 8;          // lanes per node
  int gl = blockIdx.x * 256 + threadIdx.x;
  int node = gl / G;
  if (node >= N_NODES) return;
  int fl = (gl % G) * 8;
  int beg = rowptr[node], end = beg + cnt[node];
  float acc[8] = {0.f, 0.f, 0.f, 0.f, 0.f, 0.f, 0.f, 0.f};
  int i = beg;
  for (; i + 1 < end; i += 2) {
    int2 e0 = csr_ew[i], e1 = csr_ew[i + 1];
    float w0 = __int_as_float(e0.y), w1 = __int_as_float(e1.y);
    ushort8 v0 = *(const ushort8*)&src_t[(size_t)e0.x * sp + fl];
    ushort8 v1 = *(const ushort8*)&src_t[(size_t)e1.x * sp + fl];
#pragma unroll
    for (int j = 0; j < 8; ++j) acc[j] += w0 * bf2f(v0[j]) + w1 * bf2f(v1[j]);
  }
  if (i < end) {
    int2 e0 = csr_ew[i];
    float w0 = __int_as_float(e0.y);
    ushort8 v0 = *(const ushort8*)&src_t[(size_t)e0.x * sp + fl];
#pragma unroll
    for (int j = 0; j < 8; ++j) acc[j] += w0 * bf2f(v0[j]);
  }
  ushort8 o;
#pragma unroll
  for (int j = 0; j < 8; ++j) o[j] = f2bf(acc[j]);
  *(ushort8*)&dst_t[(size_t)node * dp + fl] = o;
}

// 16-wide fp32 SpMM with addend (Horner for layer 3); weights pre-scaled
__global__ __launch_bounds__(256) void k_spmm16(const float* __restrict__ src_t, int sp,
                                                const float* __restrict__ addend, int ap,
                                                const float* __restrict__ b3,
                                                float* __restrict__ out, int op,
                                                const int* __restrict__ rowptr,
                                                const int* __restrict__ cnt,
                                                const int2* __restrict__ csr_ew) {
  int idx = blockIdx.x * 256 + threadIdx.x;
  if (idx >= N_NODES * 16) return;
  int node = idx >> 4, f = idx & 15;
  int beg = rowptr[node], ne = cnt[node];
  float acc = 0.f;
  for (int i = 0; i < ne; ++i) {
    int2 e = csr_ew[beg + i];
    acc += __int_as_float(e.y) * src_t[(size_t)e.x * sp + f];
  }
  float r = acc + addend[(size_t)node * ap + f];
  if (b3) r += b3[f];
  out[(size_t)node * op + f] = r;
}

// ---- bf16 MFMA GEMM (R10/R12-proven core): Cout = A*BT^T (+ Cinit) ----
// 128x128 tile, BK=32 double-buffered, 4 waves (2x2), 4x4 MFMA 16x16x32.
// global_load_lds width 16; XOR swizzle; LDS-staged coalesced bf16 epilogue.
// STATS is a COMPILE-TIME template arg; STATS=0 codegen == validated R10
// kernel. (R13's ATOMIC K-split variant REGRESSED — removed.)

template <int STATS>
__global__ __launch_bounds__(256, 4) void k_gemm(
    const unsigned short* __restrict__ A, int lda,
    const unsigned short* __restrict__ BT, int ldb,
    const unsigned short* __restrict__ Cinit, int ldci,
    void* __restrict__ Cout, int ldc, int cbf16,
    int M, int Nout, int K,
    const float* __restrict__ bias, int do_elu,
    float* __restrict__ stats_out, int stats_off) {
  __shared__ __align__(16) unsigned short smem[128 * EPITCH];  // 34816 B
  int tid = threadIdx.x;
  int wave = tid >> 6, lane = tid & 63;
  int wm = wave >> 1, wn = wave & 1;
  int l15 = lane & 15, quad = lane >> 4;
  int im = blockIdx.y, in_ = blockIdx.x;

  f32x4 acc[4][4];
  if (Cinit) {
    {
      int r = tid >> 1, hf = tid & 1;
      const unsigned short* gsrc =
          &Cinit[(size_t)(im * 128 + r) * ldci + in_ * 128 + hf * 64];
#pragma unroll
      for (int v = 0; v < 8; ++v)
        *(ushort8*)&smem[r * EPITCH + hf * 64 + v * 8] = *(const ushort8*)&gsrc[v * 8];
    }
    __syncthreads();
#pragma unroll
    for (int i = 0; i < 4; ++i)
#pragma unroll
      for (int j = 0; j < 4; ++j)
#pragma unroll
        for (int reg = 0; reg < 4; ++reg)
          acc[i][j][reg] =
              bf2f(smem[(wm * 64 + i * 16 + quad * 4 + reg) * EPITCH + wn * 64 + j * 16 + l15]);
    __syncthreads();
  } else {
#pragma unroll
    for (int i = 0; i < 4; ++i)
#pragma unroll
      for (int j = 0; j < 4; ++j) acc[i][j] = (f32x4){0.f, 0.f, 0.f, 0.f};
  }

  int srow = tid >> 2;                                       // 0..63
  int sl = (tid & 3) ^ (srow & 3) ^ ((srow >> 2) & 3);       // swizzled chunk
  const unsigned short* gA0 = &A[(size_t)(im * 128 + srow) * lda + sl * 8];
  const unsigned short* gA1 = &A[(size_t)(im * 128 + 64 + srow) * lda + sl * 8];
  const unsigned short* gB0 = &BT[(size_t)(in_ * 128 + srow) * ldb + sl * 8];
  const unsigned short* gB1 = &BT[(size_t)(in_ * 128 + 64 + srow) * ldb + sl * 8];
  unsigned short* ldsA = smem;            // [2][4096]
  unsigned short* ldsB = smem + 8192;     // [2][4096]
  int woff0 = (wave * 64) * 8;
  int woff1 = (256 + wave * 64) * 8;
  int rsl = (quad ^ (l15 & 3) ^ (l15 >> 2)) * 8;

  auto stage = [&](int k0, int p) {
    ASYNC16(gA0 + k0, &ldsA[p * 4096 + woff0]);
    ASYNC16(gA1 + k0, &ldsA[p * 4096 + woff1]);
    ASYNC16(gB0 + k0, &ldsB[p * 4096 + woff0]);
    ASYNC16(gB1 + k0, &ldsB[p * 4096 + woff1]);
  };
  auto compute = [&](int p) {
    short8 af[4], bf[4];
#pragma unroll
    for (int i = 0; i < 4; ++i)
      af[i] = *(const short8*)&ldsA[p * 4096 + (wm * 64 + i * 16 + l15) * 32 + rsl];
#pragma unroll
    for (int j = 0; j < 4; ++j)
      bf[j] = *(const short8*)&ldsB[p * 4096 + (wn * 64 + j * 16 + l15) * 32 + rsl];
#pragma unroll
    for (int i = 0; i < 4; ++i)
#pragma unroll
      for (int j = 0; j < 4; ++j)
        acc[i][j] = __builtin_amdgcn_mfma_f32_16x16x32_bf16(af[i], bf[j], acc[i][j], 0, 0, 0);
  };

  stage(0, 0);
  __syncthreads();
  int p = 0;
  for (int k0 = 32; k0 < K; k0 += 32) {
    stage(k0, p ^ 1);
    compute(p);
    __syncthreads();
    p ^= 1;
  }
  compute(p);
  __syncthreads();

  if (cbf16) {
    float sl0[4], sl2[4];
    if (STATS) {
#pragma unroll
      for (int j = 0; j < 4; ++j) { sl0[j] = 0.f; sl2[j] = 0.f; }
    }
#pragma unroll
    for (int i = 0; i < 4; ++i)
#pragma unroll
      for (int j = 0; j < 4; ++j) {
        int cg = in_ * 128 + wn * 64 + j * 16 + l15;
        float bv = bias ? bias[cg] : 0.f;
#pragma unroll
        for (int reg = 0; reg < 4; ++reg) {
          float v = acc[i][j][reg] + bv;
          if (do_elu) v = v > 0.f ? v : expm1f(v);
          unsigned short b = f2bf(v);
          smem[(wm * 64 + i * 16 + quad * 4 + reg) * EPITCH + wn * 64 + j * 16 + l15] = b;
          if (STATS) {
            int r = im * 128 + wm * 64 + i * 16 + quad * 4 + reg;
            if (r < M) {
              float vq = bf2f(b);
              sl0[j] += vq; sl2[j] += vq * vq;
            }
          }
        }
      }
    __syncthreads();
    {
      int r = tid >> 1, hf = tid & 1;
      unsigned short* gdst =
          (unsigned short*)Cout + (size_t)(im * 128 + r) * ldc + in_ * 128 + hf * 64;
#pragma unroll
      for (int v = 0; v < 8; ++v)
        *(ushort8*)&gdst[v * 8] = *(const ushort8*)&smem[r * EPITCH + hf * 64 + v * 8];
    }
    if (STATS) {
      __syncthreads();   // tile fully consumed -> reuse smem as f32 scratch
      float* fs = (float*)smem;           // [2][8][128] = 8 KB
      int slot = wm * 4 + quad;           // 0..7
#pragma unroll
      for (int j = 0; j < 4; ++j) {
        int c = wn * 64 + j * 16 + l15;   // 0..127
        fs[slot * 128 + c] = sl0[j];
        fs[1024 + slot * 128 + c] = sl2[j];
      }
      __syncthreads();
      if (tid < 128) {
        float a0 = 0.f, a1 = 0.f;
#pragma unroll
        for (int s = 0; s < 8; ++s) {
          a0 += fs[s * 128 + tid];
          a1 += fs[1024 + s * 128 + tid];
        }
        atomicAdd(&stats_out[stats_off + in_ * 128 + tid], a0);
        atomicAdd(&stats_out[HID + stats_off + in_ * 128 + tid], a1);
      }
    }
  } else {
#pragma unroll
    for (int i = 0; i < 4; ++i) {
      int r0 = im * 128 + wm * 64 + i * 16 + quad * 4;
#pragma unroll
      for (int j = 0; j < 4; ++j) {
        int c = in_ * 128 + wn * 64 + j * 16 + l15;
        if (c < Nout) {
#pragma unroll
          for (int reg = 0; reg < 4; ++reg) {
            int r = r0 + reg;
            if (r < M) {
              float v = acc[i][j][reg];
              if (bias) v += bias[c];
              if (do_elu) v = v > 0.f ? v : expm1f(v);
              ((float*)Cout)[(size_t)r * ldc + c] = v;
            }
          }
        }
      }
    }
  }
}

// ---------------- GraphNorm finalize ----------------

__global__ __launch_bounds__(256) void k_finalize(const float* __restrict__ g,
                                                  const float* __restrict__ be,
                                                  const float* __restrict__ a,
                                                  float* __restrict__ stats) {
  int f = blockIdx.x * 256 + threadIdx.x;
  if (f < HID) {
    float m = stats[f] / (float)N_NODES;
    float ex2 = stats[HID + f] / (float)N_NODES;
    float av = a[f];
    float var = ex2 - 2.f * av * m * m + av * av * m * m;  // E[(x-a*m)^2]
    float alpha = g[f] * rsqrtf(var + EPSN);
    stats[2 * HID + f] = alpha;
    stats[3 * HID + f] = be[f] - alpha * av * m;
  }
}

// ---------------- launch ----------------

extern "C" void kernel_launch(void* const* d_in, const int* in_sizes, int n_in,
                              void* d_out, int out_size, void* d_ws, size_t ws_size,
                              hipStream_t stream) {
  const float* x   = (const float*)d_in[0];
  const int*   ei  = (const int*)d_in[1];
  const float* w   = (const float*)d_in[2];
  const float* W1  = (const float*)d_in[3];
  const float* b1  = (const float*)d_in[4];
  const float* g1  = (const float*)d_in[5];
  const float* be1 = (const float*)d_in[6];
  const float* a1  = (const float*)d_in[7];
  const float* W2  = (const float*)d_in[8];
  const float* b2  = (const float*)d_in[9];
  const float* g2  = (const float*)d_in[10];
  const float* be2 = (const float*)d_in[11];
  const float* a2  = (const float*)d_in[12];
  const float* W3  = (const float*)d_in[13];
  const float* b3  = (const float*)d_in[14];
  float* out = (float*)d_out;

  const int* srcI = ei;
  const int* dstI = ei + N_EDGES;

  char* base = (char*)d_ws;
  size_t off = 0;
  auto alloc = [&](size_t bytes) -> char* {
    char* p = base + off;
    off += (bytes + 255) & ~(size_t)255;
    return p;
  };

  // small buffers
  float* deg      = (float*)alloc(N_NODES * 4);
  int*   cnt      = (int*)alloc(N_NODES * 4);
  float* cnt_inv  = (float*)alloc(N_NODES * 4);
  float* normw    = (float*)alloc(N_EDGES * 4);
  int*   rowptr   = (int*)alloc((N_NODES + 1) * 4);
  int*   fill     = (int*)alloc(N_NODES * 4);
  int*   bsums    = (int*)alloc(64 * 4);
  int2*  csr_ew   = (int2*)alloc((size_t)N_EDGES * 8);
  float* stats    = (float*)alloc(4 * HID * 4);
  float* ck       = (float*)alloc(4 * HID * 4);
  float* ck3      = (float*)alloc(64 * 4);
  // weights (~9.7 MB)
  __hip_bfloat16* W1T = (__hip_bfloat16*)alloc((size_t)1024 * 512 * 2);
  __hip_bfloat16* W2T = (__hip_bfloat16*)alloc((size_t)1024 * 4096 * 2);
  __hip_bfloat16* W3T = (__hip_bfloat16*)alloc((size_t)128 * 1024 * 2);
  // full node tables (102.5 MB each)
  const size_t FT = (size_t)NPAD * HID * 2;
  unsigned short* T0 = (unsigned short*)alloc(FT);
  unsigned short* T1 = (unsigned short*)alloc(FT);
  size_t rem = (ws_size > off) ? (ws_size - off) : 0;
  bool full = rem >= FT + 1024;
  unsigned short *T2 = nullptr, *Q = nullptr, *R = nullptr;
  int wcols = 0;
  if (full) {
    T2 = (unsigned short*)alloc(FT);
  } else {
    wcols = 512;
    if (rem < 2 * (size_t)NPAD * 512 * 2 + 1024) wcols = 256;
    if (wcols == 256 && rem < 2 * (size_t)NPAD * 256 * 2 + 1024) wcols = 128;
    Q = (unsigned short*)alloc((size_t)NPAD * wcols * 2);
    R = (unsigned short*)alloc((size_t)NPAD * wcols * 2);
  }
  // layer-3 scratch carved from T0 (dead after last layer-2 GEMM)
  float* Z  = (float*)T0;
  float* t0 = (float*)((char*)T0 + (size_t)16 * 1024 * 1024);
  float* t1 = (float*)((char*)T0 + (size_t)24 * 1024 * 1024);
  (void)n_in; (void)in_sizes; (void)out_size;

  const int EB = (N_EDGES + 255) / 256;

  // graph preprocessing + CSR
  (void)hipMemsetAsync(deg, 0, N_NODES * 4, stream);
  (void)hipMemsetAsync(cnt, 0, N_NODES * 4, stream);
  (void)hipMemsetAsync(fill, 0, N_NODES * 4, stream);
  k_deg_cnt<<<EB, 256, 0, stream>>>(dstI, w, deg, cnt);
  k_normw_cntinv<<<EB, 256, 0, stream>>>(srcI, dstI, w, deg, cnt, normw, cnt_inv);
  k_scan_a<<<49, 1024, 0, stream>>>(cnt, rowptr, bsums);
  k_scan_b<<<1, 64, 0, stream>>>(bsums, 49);
  k_scan_c<<<49, 1024, 0, stream>>>(rowptr, bsums);
  k_fill<<<EB, 256, 0, stream>>>(srcI, dstI, normw, cnt_inv, rowptr, fill, csr_ew);

  // W1 repack (W2/W3 repacks happen after the respective finalize — alpha fold)
  k_transpose_bf16<<<dim3(512 / 32, 1024 / 32), dim3(32, 8), 0, stream>>>(W1, W1T, 512, 1024);

  const unsigned short* W2Tu = (const unsigned short*)W2T;

  // ---- layer 1: Xcat [N, 4*128] in T1 (pitch 512), GEMM K=512 -> T0 (+stats) ----
  k_x_to_bf16<<<(N_NODES * FIN / 4 + 255) / 256, 256, 0, stream>>>(x, T1);
  {
    int blocks = (N_NODES * 16 + 255) / 256;
    for (int k = 1; k <= 3; ++k)
      k_spmm_v<128><<<blocks, 256, 0, stream>>>(
          T1 + (k - 1) * FIN, 512, T1 + k * FIN, 512,
          rowptr, cnt, csr_ew);
  }
  (void)hipMemsetAsync(stats, 0, 2 * HID * 4, stream);
  k_gemm<1><<<dim3(8, MT), 256, 0, stream>>>(
      T1, 512, (const unsigned short*)W1T, 512,
      nullptr, 0, T0, HID, 1, N_NODES, HID, 512, b1, 1, stats, 0);
  k_finalize<<<4, 256, 0, stream>>>(g1, be1, a1, stats);
  // GraphNorm-1 folded into W2 (alpha-scaled repack + ck bias)
  k_transpose_scale_bf16<<<dim3(4096 / 32, 1024 / 32), dim3(32, 8), 0, stream>>>(
      W2, W2T, 4096, 1024, stats + 2 * HID);
  (void)hipMemsetAsync(ck, 0, 4 * HID * 4, stream);
  k_ck_part<<<dim3(4, 64), 256, 0, stream>>>(W2, stats + 3 * HID, b2, ck);

  // ---- layer 2: Horner; hop-0 GEMM fuses ELU + column stats ----
  if (full) {
    const int SPB = (N_NODES * 128 + 255) / 256;
    k_gemm<0><<<dim3(8, MT), 256, 0, stream>>>(
        T0, 1024, W2Tu + 3 * 1024, 4096,
        nullptr, 0, T1, 1024, 1, N_NODES, 1024, 1024, ck + 3 * 1024, 0, nullptr, 0);
    k_spmm_v<1024><<<SPB, 256, 0, stream>>>(T1, 1024, T2, 1024,
                                            rowptr, cnt, csr_ew);
    k_gemm<0><<<dim3(8, MT), 256, 0, stream>>>(
        T0, 1024, W2Tu + 2 * 1024, 4096,
        T2, 1024, T1, 1024, 1, N_NODES, 1024, 1024, ck + 2 * 1024, 0, nullptr, 0);
    k_spmm_v<1024><<<SPB, 256, 0, stream>>>(T1, 1024, T2, 1024,
                                            rowptr, cnt, csr_ew);
    k_gemm<0><<<dim3(8, MT), 256, 0, stream>>>(
        T0, 1024, W2Tu + 1 * 1024, 4096,
        T2, 1024, T1, 1024, 1, N_NODES, 1024, 1024, ck + 1 * 1024, 0, nullptr, 0);
    k_spmm_v<1024><<<SPB, 256, 0, stream>>>(T1, 1024, T2, 1024,
                                            rowptr, cnt, csr_ew);
    (void)hipMemsetAsync(stats, 0, 2 * HID * 4, stream);
    k_gemm<1><<<dim3(8, MT), 256, 0, stream>>>(
        T0, 1024, W2Tu + 0 * 1024, 4096,
        T2, 1024, T1, 1024, 1, N_NODES, 1024, 1024, ck + 0 * 1024, 1, stats, 0);
  } else {
    auto spmm_w = [&](const unsigned short* s, unsigned short* d) {
      int blocks = (N_NODES * (wcols / 8) + 255) / 256;
      if (wcols == 512)
        k_spmm_v<512><<<blocks, 256, 0, stream>>>(s, wcols, d, wcols,
            rowptr, cnt, csr_ew);
      else if (wcols == 256)
        k_spmm_v<256><<<blocks, 256, 0, stream>>>(s, wcols, d, wcols,
            rowptr, cnt, csr_ew);
      else
        k_spmm_v<128><<<blocks, 256, 0, stream>>>(s, wcols, d, wcols,
            rowptr, cnt, csr_ew);
    };
    (void)hipMemsetAsync(stats, 0, 2 * HID * 4, stream);
    for (int c = 0; c < HID; c += wcols) {
      const unsigned short* Wb = W2Tu + (size_t)c * 4096;
      k_gemm<0><<<dim3(wcols / 128, MT), 256, 0, stream>>>(
          T0, 1024, Wb + 3 * 1024, 4096,
          nullptr, 0, Q, wcols, 1, N_NODES, wcols, 1024, ck + 3 * 1024 + c, 0, nullptr, 0);
      spmm_w(Q, R);
      k_gemm<0><<<dim3(wcols / 128, MT), 256, 0, stream>>>(
          T0, 1024, Wb + 2 * 1024, 4096,
          R, wcols, Q, wcols, 1, N_NODES, wcols, 1024, ck + 2 * 1024 + c, 0, nullptr, 0);
      spmm_w(Q, R);
      k_gemm<0><<<dim3(wcols / 128, MT), 256, 0, stream>>>(
          T0, 1024, Wb + 1 * 1024, 4096,
          R, wcols, Q, wcols, 1, N_NODES, wcols, 1024, ck + 1 * 1024 + c, 0, nullptr, 0);
      spmm_w(Q, R);
      k_gemm<1><<<dim3(wcols / 128, MT), 256, 0, stream>>>(
          T0, 1024, Wb + 0 * 1024, 4096,
          R, wcols, T1 + c, 1024, 1, N_NODES, wcols, 1024, ck + 0 * 1024 + c, 1, stats, c);
    }
  }
  k_finalize<<<4, 256, 0, stream>>>(g2, be2, a2, stats);
  // GraphNorm-2 folded into W3 (alpha-scaled repack + ck3 bias)
  k_packw3<<<(65536 + 255) / 256, 256, 0, stream>>>(W3, W3T, stats + 2 * HID);
  k_ck3<<<64, 256, 0, stream>>>(W3, stats + 3 * HID, ck3);

  // ---- layer 3: project (Z in T0 region, bias=ck3) then Horner width 16 ----
  k_gemm<0><<<dim3(1, MT), 256, 0, stream>>>(
      T1, 1024, (const unsigned short*)W3T, 1024,
      nullptr, 0, Z, 64, 0, N_NODES, 64, 1024, ck3, 0, nullptr, 0);
  const int SB = (N_NODES * 16 + 255) / 256;
  k_spmm16<<<SB, 256, 0, stream>>>(Z + 48, 64, Z + 32, 64, nullptr, t0, 16,
                                   rowptr, cnt, csr_ew);
  k_spmm16<<<SB, 256, 0, stream>>>(t0, 16, Z + 16, 64, nullptr, t1, 16,
                                   rowptr, cnt, csr_ew);
  k_spmm16<<<SB, 256, 0, stream>>>(t1, 16, Z + 0, 64, b3, out, 16,
                                   rowptr, cnt, csr_ew);
}